// Round 8
// baseline (373.299 us; speedup 1.0000x reference)
//
#include <hip/hip_runtime.h>
#include <math.h>

#define N0 16
#define N1 200
#define N2 200
#define NPIX (N1 * N2)            // 40000
#define NVOX (N0 * NPIX)          // 640000
#define NUM_RAD 223
#define NUM_PHI 190
#define NUM_T 351
#define NSINO (N0 * NUM_PHI * NUM_RAD)  // 677920
#define ORG1F (-199.0f)
#define ORG2F (-199.0f)
#define QSTRIDE (201 * 201 * 4)   // padded quad-interleaved slice group
#define BP_CHUNK 10
#define BP_NCH 19                 // 190 = 19 * 10

// ---------------- constants: replicate numpy linspace / cos / gaussian ----------------
__global__ void init_consts(float* __restrict__ cosb, float* __restrict__ sinb,
                            float* __restrict__ rvb, float* __restrict__ gwb) {
    int t = threadIdx.x;
    const double PI = 3.14159265358979311599796346854418516159;
    if (t < NUM_PHI) {
        double step = PI / 190.0;             // np.linspace(0, pi, 190, endpoint=False)
        float phif = (float)((double)t * step);
        cosb[t] = (float)cos((double)phif);   // np.cos on float32 input
        sinb[t] = (float)sin((double)phif);
    }
    if (t < NUM_RAD) {
        double step = 400.0 / 222.0;          // np.linspace(-200, 200, 223)
        float rv = (float)(-200.0 + (double)t * step);
        if (t == NUM_RAD - 1) rv = 200.0f;    // linspace endpoint fixup
        rvb[t] = rv;
    }
    if (t == 0) {
        double sig = 4.5 / (2.35 * 2.0);
        double g[9], ssum = 0.0;
        for (int k = 0; k < 9; ++k) { double d = (double)(k - 4) / sig; g[k] = exp(-0.5 * d * d); ssum += g[k]; }
        for (int k = 0; k < 9; ++k) gwb[k] = (float)(g[k] / ssum);
    }
}

// ---------------- separable gaussian, forward (symmetric pad) ----------------
__global__ void smooth_fwd(const float* __restrict__ in, float* __restrict__ out,
                           const float* __restrict__ gwb, int n, int stride) {
    int e = blockIdx.x * 256 + threadIdx.x;
    if (e >= NVOX) return;
    int a = (e / stride) % n;
    int base = e - a * stride;
    float sum = 0.f;
#pragma unroll
    for (int k = 0; k < 9; ++k) {
        int q = a + k - 4;
        q = (q < 0) ? (-1 - q) : ((q >= n) ? (2 * n - 1 - q) : q);
        sum = __fadd_rn(sum, __fmul_rn(gwb[k], in[base + q * stride]));
    }
    out[e] = sum;
}

// axis-2 pass writing quad-interleaved padded layouts:
//   P [q][i1][i2][s]  and  PT[q][i2][i1][s],  201x201 with edge replication.
__global__ void smooth_fwd2_quad(const float* __restrict__ in, float* __restrict__ P,
                                 float* __restrict__ PT, const float* __restrict__ gwb) {
    int e = blockIdx.x * 256 + threadIdx.x;
    if (e >= NVOX) return;
    int i2 = e % N2;
    int base = e - i2;
    float sum = 0.f;
#pragma unroll
    for (int k = 0; k < 9; ++k) {
        int q = i2 + k - 4;
        q = (q < 0) ? (-1 - q) : ((q >= N2) ? (2 * N2 - 1 - q) : q);
        sum = __fadd_rn(sum, __fmul_rn(gwb[k], in[base + q]));
    }
    int i0 = e / NPIX;
    int rem = e - i0 * NPIX;
    int i1 = rem / N2;
    int qd = i0 >> 2, s = i0 & 3;
    float* Pq  = P  + qd * QSTRIDE;
    float* PTq = PT + qd * QSTRIDE;
    bool e1 = (i1 == 199), e2 = (i2 == 199);
    Pq[(i1 * 201 + i2) * 4 + s] = sum;
    if (e2) Pq[(i1 * 201 + 200) * 4 + s] = sum;
    if (e1) Pq[(200 * 201 + i2) * 4 + s] = sum;
    if (e1 && e2) Pq[(200 * 201 + 200) * 4 + s] = sum;
    PTq[(i2 * 201 + i1) * 4 + s] = sum;
    if (e1) PTq[(i2 * 201 + 200) * 4 + s] = sum;
    if (e2) PTq[(200 * 201 + i1) * 4 + s] = sum;
    if (e1 && e2) PTq[(200 * 201 + 200) * 4 + s] = sum;
}

// ---------------- separable gaussian, adjoint (pad-transpose fold) ----------------
__device__ __forceinline__ float adj_u(const float* __restrict__ in, const float* __restrict__ gwb,
                                       int base, int stride, int n, int j) {
    float r = 0.f;
#pragma unroll
    for (int k = 0; k < 9; ++k) {
        int i = j - k;
        if (i >= 0 && i < n) r = __fadd_rn(r, __fmul_rn(gwb[k], in[base + i * stride]));
    }
    return r;
}

__global__ void smooth_adj(const float* __restrict__ in, float* __restrict__ out,
                           const float* __restrict__ gwb, int n, int stride) {
    int e = blockIdx.x * 256 + threadIdx.x;
    if (e >= NVOX) return;
    int a = (e / stride) % n;
    int base = e - a * stride;
    float v = adj_u(in, gwb, base, stride, n, a + 4);
    if (a < 4)      v = __fadd_rn(v, adj_u(in, gwb, base, stride, n, 3 - a));
    if (a >= n - 4) v = __fadd_rn(v, adj_u(in, gwb, base, stride, n, 2 * n + 3 - a));
    out[e] = v;
}

// final axis-0 adjoint pass fused with  out = x * v / sens
__global__ void smooth_adj0_final(const float* __restrict__ in, const float* __restrict__ x,
                                  const float* __restrict__ sens, const float* __restrict__ gwb,
                                  float* __restrict__ out) {
    int e = blockIdx.x * 256 + threadIdx.x;
    if (e >= NVOX) return;
    int a = e / NPIX;
    int base = e - a * NPIX;
    float v = adj_u(in, gwb, base, NPIX, N0, a + 4);
    if (a < 4)  v = __fadd_rn(v, adj_u(in, gwb, base, NPIX, N0, 3 - a));
    if (a >= 12) v = __fadd_rn(v, adj_u(in, gwb, base, NPIX, N0, 35 - a));
    out[e] = __fdiv_rn(__fmul_rn(x[e], v), sens[e]);
}

// geometry for one t-sample (shared by pipeline stages)
#define GEOM(K, W00, W10, W01, W11, M, O)                                        \
    {                                                                            \
        float tv = (float)(2 * (K) - 350);                                       \
        float ix = __fmul_rn(__fsub_rn(__fadd_rn(A, __fmul_rn(tv, c)), ORG1F), 0.5f); \
        float iy = __fmul_rn(__fsub_rn(__fadd_rn(B, __fmul_rn(tv, sp)), ORG2F), 0.5f); \
        bool valid = (ix >= 0.f && ix <= 199.f && iy >= 0.f && iy <= 199.f);     \
        float fx = floorf(ix), fy = floorf(iy);                                  \
        int ii = (int)fx, jj = (int)fy;                                          \
        float fi = ix - fx, fj = iy - fy;                                        \
        int ii0 = min(max(ii, 0), 199), jj0 = min(max(jj, 0), 199);              \
        int rowi = useT ? jj0 : ii0;                                             \
        int coli = useT ? ii0 : jj0;                                             \
        O = (rowi * 201 + coli) * 4;                                             \
        W00 = (1.f - fi) * (1.f - fj); W10 = fi * (1.f - fj);                    \
        W01 = (1.f - fi) * fj;         W11 = fi * fj;                            \
        M = valid ? 1.f : 0.f;                                                   \
    }

// ---------------- forward projection + ratio, fused ----------------
// block (256,4) = 1024 threads: x = radial bin r, y = t-quarter; grid (phi, quad).
// 2 blocks/CU -> 32 waves/CU (100% occupancy). Quarters combine via LDS;
// quarter 0 does the ratio epilogue. Software-pipelined float4 quad loads.
__global__ __launch_bounds__(1024, 8)
void project_ratio(const float* __restrict__ P, const float* __restrict__ PT,
                   const float* __restrict__ data,
                   const float* __restrict__ contam, const float* __restrict__ mult,
                   const float* __restrict__ cosb, const float* __restrict__ sinb,
                   const float* __restrict__ rvb, float* __restrict__ zt) {
    int phi = blockIdx.x;
    int qd = blockIdx.y;
    int i0 = qd * 4;
    int r = threadIdx.x;
    int quar = threadIdx.y;
    bool active = (r < NUM_RAD);

    __shared__ float part[3][4][256];

    float sums[4] = {0.f, 0.f, 0.f, 0.f};
    float c = cosb[phi], sp = sinb[phi];

    bool useT = fabsf(sp) > fabsf(c);
    const float* basep = (useT ? PT : P) + qd * QSTRIDE;
    int dI = useT ? 4 : 804;   // float-offset step for ii+1
    int dJ = useT ? 804 : 4;   // float-offset step for jj+1

    if (active) {
        float rv = rvb[r];
        float A = __fmul_rn(rv, -sp);   // RV * (-s)
        float B = __fmul_rn(rv, c);     // RV * c

        // conservative valid-t window
        float tlo = -350.f, thi = 350.f;
        bool empty = false;
        if (fabsf(c) > 1e-6f) {
            float a0 = (-199.f - A) / c, b0 = (199.f - A) / c;
            tlo = fmaxf(tlo, fminf(a0, b0)); thi = fminf(thi, fmaxf(a0, b0));
        } else if (fabsf(A) > 199.5f) empty = true;
        if (fabsf(sp) > 1e-6f) {
            float a0 = (-199.f - B) / sp, b0 = (199.f - B) / sp;
            tlo = fmaxf(tlo, fminf(a0, b0)); thi = fminf(thi, fmaxf(a0, b0));
        } else if (fabsf(B) > 199.5f) empty = true;

        int klo = max(0, (int)floorf((tlo + 350.f) * 0.5f) - 1);
        int khi = min(NUM_T - 1, (int)ceilf((thi + 350.f) * 0.5f) + 1);

        if (!empty && klo <= khi) {
            int L = khi - klo + 1;
            int kbeg = klo + (L * quar) / 4;
            int kend = klo + (L * (quar + 1)) / 4 - 1;
            if (kbeg <= kend) {
                float w00, w10, w01, w11, m;
                int o;
                GEOM(kbeg, w00, w10, w01, w11, m, o);
                float4 L00 = *(const float4*)(basep + o);
                float4 L10 = *(const float4*)(basep + o + dI);
                float4 L01 = *(const float4*)(basep + o + dJ);
                float4 L11 = *(const float4*)(basep + o + dI + dJ);
#pragma unroll 2
                for (int k = kbeg; k < kend; ++k) {
                    float nw00, nw10, nw01, nw11, nm;
                    int no;
                    GEOM(k + 1, nw00, nw10, nw01, nw11, nm, no);
                    float4 N00 = *(const float4*)(basep + no);
                    float4 N10 = *(const float4*)(basep + no + dI);
                    float4 N01 = *(const float4*)(basep + no + dJ);
                    float4 N11 = *(const float4*)(basep + no + dI + dJ);
                    float v0 = w00 * L00.x + w10 * L10.x + w01 * L01.x + w11 * L11.x;
                    float v1 = w00 * L00.y + w10 * L10.y + w01 * L01.y + w11 * L11.y;
                    float v2 = w00 * L00.z + w10 * L10.z + w01 * L01.z + w11 * L11.z;
                    float v3 = w00 * L00.w + w10 * L10.w + w01 * L01.w + w11 * L11.w;
                    sums[0] = __fadd_rn(sums[0], __fmul_rn(v0, m));
                    sums[1] = __fadd_rn(sums[1], __fmul_rn(v1, m));
                    sums[2] = __fadd_rn(sums[2], __fmul_rn(v2, m));
                    sums[3] = __fadd_rn(sums[3], __fmul_rn(v3, m));
                    w00 = nw00; w10 = nw10; w01 = nw01; w11 = nw11; m = nm;
                    L00 = N00; L10 = N10; L01 = N01; L11 = N11;
                }
                float v0 = w00 * L00.x + w10 * L10.x + w01 * L01.x + w11 * L11.x;
                float v1 = w00 * L00.y + w10 * L10.y + w01 * L01.y + w11 * L11.y;
                float v2 = w00 * L00.z + w10 * L10.z + w01 * L01.z + w11 * L11.z;
                float v3 = w00 * L00.w + w10 * L10.w + w01 * L01.w + w11 * L11.w;
                sums[0] = __fadd_rn(sums[0], __fmul_rn(v0, m));
                sums[1] = __fadd_rn(sums[1], __fmul_rn(v1, m));
                sums[2] = __fadd_rn(sums[2], __fmul_rn(v2, m));
                sums[3] = __fadd_rn(sums[3], __fmul_rn(v3, m));
            }
        }
    }

    if (quar > 0) {
#pragma unroll
        for (int s = 0; s < 4; ++s) part[quar - 1][s][r] = sums[s];
    }
    __syncthreads();
    if (quar == 0 && active) {
#pragma unroll
        for (int s = 0; s < 4; ++s) {
            float tot = __fadd_rn(__fadd_rn(sums[s], part[0][s][r]),
                                  __fadd_rn(part[1][s][r], part[2][s][r]));
            float proj = __fmul_rn(tot, 2.0f);  // * STEP
            int sl = i0 + s;
            int idx = (sl * NUM_PHI + phi) * NUM_RAD + r;
            float ex = __fadd_rn(__fmul_rn(mult[idx], proj), contam[idx]);
            float zval = __fmul_rn(mult[idx], __fdiv_rn(data[idx], ex));
            zt[(phi * NUM_RAD + r) * N0 + sl] = zval;
        }
    }
}

// ---------------- adjoint projection, gather form, branch-free ----------------
// grid (ceil(NPIX/256), 19): thread = pixel, blockIdx.y = phi-chunk (uniform).
// 4 j-candidates x 3 k-candidates (provable superset: |k - tc| < 1.415 with
// kc = round(tc) covers all nonzero-weight samples). 16 unconditional float4
// loads batched before the FMA block.
__global__ __launch_bounds__(256, 4)
void backproject(const float* __restrict__ zt, const float* __restrict__ cosb,
                 const float* __restrict__ sinb, const float* __restrict__ rvb,
                 float* __restrict__ bp) {
    int pix = blockIdx.x * 256 + threadIdx.x;
    if (pix >= NPIX) return;
    int pc = blockIdx.y;
    int i1 = pix / N2;
    int i2 = pix - i1 * N2;
    float X1 = 2.f * (float)i1 - 199.f;   // ORG1 + i1*VOX (exact)
    float X2 = 2.f * (float)i2 - 199.f;
    float i1f = (float)i1, i2f = (float)i2;
    float acc[N0];
#pragma unroll
    for (int i0 = 0; i0 < N0; ++i0) acc[i0] = 0.f;

    int p_end = pc * BP_CHUNK + BP_CHUNK;
    for (int p = pc * BP_CHUNK; p < p_end; ++p) {
        float c = cosb[p], sp = sinb[p];
        float tp = c * X1 + sp * X2;      // candidate location only
        float rp = c * X2 - sp * X1;
        int j0 = (int)floorf((rp + 200.f) * 0.555f);   // 222/400 == 0.555 exactly
        float tc = (tp + 350.f) * 0.5f;
        int kc = (int)floorf(tc + 0.5f);

        float wv[4];
        int jc4[4];
#pragma unroll
        for (int dj = 0; dj < 4; ++dj) {
            int j = j0 - 1 + dj;
            bool jvalid = (j >= 0) & (j <= NUM_RAD - 1);
            int jc = min(max(j, 0), NUM_RAD - 1);
            jc4[dj] = jc;
            float rv = rvb[jc];
            float A = __fmul_rn(rv, -sp);
            float B = __fmul_rn(rv, c);
            float w = 0.f;
#pragma unroll
            for (int dk = 0; dk < 3; ++dk) {
                int k = kc - 1 + dk;
                bool kvalid = (k >= 0) & (k <= NUM_T - 1);
                float tv = (float)(2 * k - 350);
                // EXACT same op sequence as forward -> identical ix/iy/validity
                float ix = __fmul_rn(__fsub_rn(__fadd_rn(A, __fmul_rn(tv, c)), ORG1F), 0.5f);
                float iy = __fmul_rn(__fsub_rn(__fadd_rn(B, __fmul_rn(tv, sp)), ORG2F), 0.5f);
                bool valid = kvalid & (ix >= 0.f) & (ix <= 199.f) & (iy >= 0.f) & (iy <= 199.f);
                // tent form == reference's floor/select chain (Sterbenz-exact)
                float wx = fmaxf(0.f, __fsub_rn(1.f, fabsf(__fsub_rn(ix, i1f))));
                float wy = fmaxf(0.f, __fsub_rn(1.f, fabsf(__fsub_rn(iy, i2f))));
                w += valid ? __fmul_rn(wx, wy) : 0.f;
            }
            wv[dj] = jvalid ? w : 0.f;
        }

        // batched unconditional loads (16 float4 in flight)
        float4 Z[4][4];
#pragma unroll
        for (int dj = 0; dj < 4; ++dj) {
            const float4* zp4 = (const float4*)(zt + (p * NUM_RAD + jc4[dj]) * N0);
            Z[dj][0] = zp4[0]; Z[dj][1] = zp4[1]; Z[dj][2] = zp4[2]; Z[dj][3] = zp4[3];
        }
#pragma unroll
        for (int dj = 0; dj < 4; ++dj) {
            float w = wv[dj];
            acc[0]  += w * Z[dj][0].x;  acc[1]  += w * Z[dj][0].y;
            acc[2]  += w * Z[dj][0].z;  acc[3]  += w * Z[dj][0].w;
            acc[4]  += w * Z[dj][1].x;  acc[5]  += w * Z[dj][1].y;
            acc[6]  += w * Z[dj][1].z;  acc[7]  += w * Z[dj][1].w;
            acc[8]  += w * Z[dj][2].x;  acc[9]  += w * Z[dj][2].y;
            acc[10] += w * Z[dj][2].z;  acc[11] += w * Z[dj][2].w;
            acc[12] += w * Z[dj][3].x;  acc[13] += w * Z[dj][3].y;
            acc[14] += w * Z[dj][3].z;  acc[15] += w * Z[dj][3].w;
        }
    }
#pragma unroll
    for (int i0 = 0; i0 < N0; ++i0)
        atomicAdd(&bp[i0 * NPIX + pix], acc[i0] * 2.0f);  // * STEP
}

extern "C" void kernel_launch(void* const* d_in, const int* in_sizes, int n_in,
                              void* d_out, int out_size, void* d_ws, size_t ws_size,
                              hipStream_t stream) {
    const float* x      = (const float*)d_in[0];
    const float* data   = (const float*)d_in[1];
    const float* contam = (const float*)d_in[2];
    const float* mult   = (const float*)d_in[3];
    const float* sens   = (const float*)d_in[4];
    float* out = (float*)d_out;

    float* W    = (float*)d_ws;
    float* s    = W;                        // 640000 (smoothed; later reused as bp)
    float* tmp  = W + NVOX;                 // 640000
    float* bp2  = W + 2 * NVOX;             // 640000
    float* zt   = W + 3 * NVOX;             // 677920
    float* P    = W + 3 * NVOX + NSINO;     // 646416
    float* PT   = P + 4 * QSTRIDE;          // 646416
    float* cosb = PT + 4 * QSTRIDE;
    float* sinb = cosb + NUM_PHI;
    float* rvb  = sinb + NUM_PHI;
    float* gwb  = rvb + NUM_RAD;

    hipLaunchKernelGGL(init_consts, dim3(1), dim3(256), 0, stream, cosb, sinb, rvb, gwb);

    // gauss3 forward: x -> s (axis0), s -> tmp (axis1), tmp -> {P, PT} (axis2 quad dual-store)
    int nb = (NVOX + 255) / 256;
    hipLaunchKernelGGL(smooth_fwd, dim3(nb), dim3(256), 0, stream, x,   s,   gwb, N0, NPIX);
    hipLaunchKernelGGL(smooth_fwd, dim3(nb), dim3(256), 0, stream, s,   tmp, gwb, N1, N2);
    hipLaunchKernelGGL(smooth_fwd2_quad, dim3(nb), dim3(256), 0, stream, tmp, P, PT, gwb);

    // forward project + ratio (writes zt): 4 slices/thread via float4, 4 t-quarters/block
    hipLaunchKernelGGL(project_ratio, dim3(NUM_PHI, N0 / 4), dim3(256, 4), 0, stream,
                       P, PT, data, contam, mult, cosb, sinb, rvb, zt);

    // backproject (gather) into bp (reuse s)
    float* bp = s;
    hipMemsetAsync(bp, 0, NVOX * sizeof(float), stream);
    int nbp = (NPIX + 255) / 256;
    hipLaunchKernelGGL(backproject, dim3(nbp, BP_NCH), dim3(256), 0, stream,
                       zt, cosb, sinb, rvb, bp);

    // gauss3 adjoint: bp -> tmp (axis2^T), tmp -> bp2 (axis1^T), bp2 -> out (axis0^T fused final)
    hipLaunchKernelGGL(smooth_adj, dim3(nb), dim3(256), 0, stream, bp,  tmp, gwb, N2, 1);
    hipLaunchKernelGGL(smooth_adj, dim3(nb), dim3(256), 0, stream, tmp, bp2, gwb, N1, N2);
    hipLaunchKernelGGL(smooth_adj0_final, dim3(nb), dim3(256), 0, stream, bp2, x, sens, gwb, out);
}

// Round 9
// 347.969 us; speedup vs baseline: 1.0728x; 1.0728x over previous
//
#include <hip/hip_runtime.h>
#include <math.h>

#define N0 16
#define N1 200
#define N2 200
#define NPIX (N1 * N2)            // 40000
#define NVOX (N0 * NPIX)          // 640000
#define NUM_RAD 223
#define NUM_PHI 190
#define NUM_T 351
#define NSINO (N0 * NUM_PHI * NUM_RAD)  // 677920
#define ORG1F (-199.0f)
#define ORG2F (-199.0f)
#define QSTRIDE (201 * 201 * 4)   // padded quad-interleaved slice group
#define BP_CHUNK 10
#define BP_NCH 19                 // 190 = 19 * 10

// ---------------- constants: replicate numpy linspace / cos / gaussian ----------------
__global__ void init_consts(float* __restrict__ cosb, float* __restrict__ sinb,
                            float* __restrict__ rvb, float* __restrict__ gwb) {
    int t = threadIdx.x;
    const double PI = 3.14159265358979311599796346854418516159;
    if (t < NUM_PHI) {
        double step = PI / 190.0;             // np.linspace(0, pi, 190, endpoint=False)
        float phif = (float)((double)t * step);
        cosb[t] = (float)cos((double)phif);   // np.cos on float32 input
        sinb[t] = (float)sin((double)phif);
    }
    if (t < NUM_RAD) {
        double step = 400.0 / 222.0;          // np.linspace(-200, 200, 223)
        float rv = (float)(-200.0 + (double)t * step);
        if (t == NUM_RAD - 1) rv = 200.0f;    // linspace endpoint fixup
        rvb[t] = rv;
    }
    if (t == 0) {
        double sig = 4.5 / (2.35 * 2.0);
        double g[9], ssum = 0.0;
        for (int k = 0; k < 9; ++k) { double d = (double)(k - 4) / sig; g[k] = exp(-0.5 * d * d); ssum += g[k]; }
        for (int k = 0; k < 9; ++k) gwb[k] = (float)(g[k] / ssum);
    }
}

// ---------------- separable gaussian, forward (symmetric pad) ----------------
__global__ void smooth_fwd(const float* __restrict__ in, float* __restrict__ out,
                           const float* __restrict__ gwb, int n, int stride) {
    int e = blockIdx.x * 256 + threadIdx.x;
    if (e >= NVOX) return;
    int a = (e / stride) % n;
    int base = e - a * stride;
    float sum = 0.f;
#pragma unroll
    for (int k = 0; k < 9; ++k) {
        int q = a + k - 4;
        q = (q < 0) ? (-1 - q) : ((q >= n) ? (2 * n - 1 - q) : q);
        sum = __fadd_rn(sum, __fmul_rn(gwb[k], in[base + q * stride]));
    }
    out[e] = sum;
}

// axis-2 pass writing quad-interleaved padded layouts:
//   P [q][i1][i2][s]  and  PT[q][i2][i1][s],  201x201 with edge replication.
__global__ void smooth_fwd2_quad(const float* __restrict__ in, float* __restrict__ P,
                                 float* __restrict__ PT, const float* __restrict__ gwb) {
    int e = blockIdx.x * 256 + threadIdx.x;
    if (e >= NVOX) return;
    int i2 = e % N2;
    int base = e - i2;
    float sum = 0.f;
#pragma unroll
    for (int k = 0; k < 9; ++k) {
        int q = i2 + k - 4;
        q = (q < 0) ? (-1 - q) : ((q >= N2) ? (2 * N2 - 1 - q) : q);
        sum = __fadd_rn(sum, __fmul_rn(gwb[k], in[base + q]));
    }
    int i0 = e / NPIX;
    int rem = e - i0 * NPIX;
    int i1 = rem / N2;
    int qd = i0 >> 2, s = i0 & 3;
    float* Pq  = P  + qd * QSTRIDE;
    float* PTq = PT + qd * QSTRIDE;
    bool e1 = (i1 == 199), e2 = (i2 == 199);
    Pq[(i1 * 201 + i2) * 4 + s] = sum;
    if (e2) Pq[(i1 * 201 + 200) * 4 + s] = sum;
    if (e1) Pq[(200 * 201 + i2) * 4 + s] = sum;
    if (e1 && e2) Pq[(200 * 201 + 200) * 4 + s] = sum;
    PTq[(i2 * 201 + i1) * 4 + s] = sum;
    if (e1) PTq[(i2 * 201 + 200) * 4 + s] = sum;
    if (e2) PTq[(200 * 201 + i1) * 4 + s] = sum;
    if (e1 && e2) PTq[(200 * 201 + 200) * 4 + s] = sum;
}

// ---------------- separable gaussian, adjoint (pad-transpose fold) ----------------
__device__ __forceinline__ float adj_u(const float* __restrict__ in, const float* __restrict__ gwb,
                                       int base, int stride, int n, int j) {
    float r = 0.f;
#pragma unroll
    for (int k = 0; k < 9; ++k) {
        int i = j - k;
        if (i >= 0 && i < n) r = __fadd_rn(r, __fmul_rn(gwb[k], in[base + i * stride]));
    }
    return r;
}

__global__ void smooth_adj(const float* __restrict__ in, float* __restrict__ out,
                           const float* __restrict__ gwb, int n, int stride) {
    int e = blockIdx.x * 256 + threadIdx.x;
    if (e >= NVOX) return;
    int a = (e / stride) % n;
    int base = e - a * stride;
    float v = adj_u(in, gwb, base, stride, n, a + 4);
    if (a < 4)      v = __fadd_rn(v, adj_u(in, gwb, base, stride, n, 3 - a));
    if (a >= n - 4) v = __fadd_rn(v, adj_u(in, gwb, base, stride, n, 2 * n + 3 - a));
    out[e] = v;
}

// final axis-0 adjoint pass fused with  out = x * v / sens
__global__ void smooth_adj0_final(const float* __restrict__ in, const float* __restrict__ x,
                                  const float* __restrict__ sens, const float* __restrict__ gwb,
                                  float* __restrict__ out) {
    int e = blockIdx.x * 256 + threadIdx.x;
    if (e >= NVOX) return;
    int a = e / NPIX;
    int base = e - a * NPIX;
    float v = adj_u(in, gwb, base, NPIX, N0, a + 4);
    if (a < 4)  v = __fadd_rn(v, adj_u(in, gwb, base, NPIX, N0, 3 - a));
    if (a >= 12) v = __fadd_rn(v, adj_u(in, gwb, base, NPIX, N0, 35 - a));
    out[e] = __fdiv_rn(__fmul_rn(x[e], v), sens[e]);
}

// geometry for one t-sample; USET selects row/col roles at compile time.
template<bool USET>
__device__ __forceinline__ void geom(int K, float A, float B, float c, float sp,
                                     float& W00, float& W10, float& W01, float& W11,
                                     float& M, int& O) {
    float tv = (float)(2 * K - 350);
    float ix = __fmul_rn(__fsub_rn(__fadd_rn(A, __fmul_rn(tv, c)), ORG1F), 0.5f);
    float iy = __fmul_rn(__fsub_rn(__fadd_rn(B, __fmul_rn(tv, sp)), ORG2F), 0.5f);
    bool valid = (ix >= 0.f && ix <= 199.f && iy >= 0.f && iy <= 199.f);
    float fx = floorf(ix), fy = floorf(iy);
    int ii = (int)fx, jj = (int)fy;
    float fi = ix - fx, fj = iy - fy;
    int ii0 = min(max(ii, 0), 199), jj0 = min(max(jj, 0), 199);
    int rowi = USET ? jj0 : ii0;
    int coli = USET ? ii0 : jj0;
    O = rowi * 804 + coli * 4;
    W00 = (1.f - fi) * (1.f - fj); W10 = fi * (1.f - fj);
    W01 = (1.f - fi) * fj;         W11 = fi * fj;
    M = valid ? 1.f : 0.f;
}

// k-loop over one t-range, 1-ahead software pipeline pinned with sched_group_barrier.
template<bool USET>
__device__ __forceinline__ void ray_loop(const float* __restrict__ basep,
                                         int kbeg, int kend, float A, float B,
                                         float c, float sp, float sums[4]) {
    constexpr int O10 = USET ? 4 : 804;   // ii+1 step (floats)
    constexpr int O01 = USET ? 804 : 4;   // jj+1 step (floats)
    float w00, w10, w01, w11, m;
    int o;
    geom<USET>(kbeg, A, B, c, sp, w00, w10, w01, w11, m, o);
    float4 L00 = *(const float4*)(basep + o);
    float4 L10 = *(const float4*)(basep + o + O10);
    float4 L01 = *(const float4*)(basep + o + O01);
    float4 L11 = *(const float4*)(basep + o + 808);
    for (int k = kbeg; k < kend; ++k) {
        float nw00, nw10, nw01, nw11, nm;
        int no;
        geom<USET>(k + 1, A, B, c, sp, nw00, nw10, nw01, nw11, nm, no);
        float4 N00 = *(const float4*)(basep + no);
        float4 N10 = *(const float4*)(basep + no + O10);
        float4 N01 = *(const float4*)(basep + no + O01);
        float4 N11 = *(const float4*)(basep + no + 808);
        float v0 = w00 * L00.x + w10 * L10.x + w01 * L01.x + w11 * L11.x;
        float v1 = w00 * L00.y + w10 * L10.y + w01 * L01.y + w11 * L11.y;
        float v2 = w00 * L00.z + w10 * L10.z + w01 * L01.z + w11 * L11.z;
        float v3 = w00 * L00.w + w10 * L10.w + w01 * L01.w + w11 * L11.w;
        sums[0] = __fadd_rn(sums[0], __fmul_rn(v0, m));
        sums[1] = __fadd_rn(sums[1], __fmul_rn(v1, m));
        sums[2] = __fadd_rn(sums[2], __fmul_rn(v2, m));
        sums[3] = __fadd_rn(sums[3], __fmul_rn(v3, m));
        w00 = nw00; w10 = nw10; w01 = nw01; w11 = nw11; m = nm;
        L00 = N00; L10 = N10; L01 = N01; L11 = N11;
        // pin: geometry VALU for k+1, then its 4 loads, then consume of k
        __builtin_amdgcn_sched_group_barrier(0x002, 28, 0);  // VALU (geom k+1)
        __builtin_amdgcn_sched_group_barrier(0x020, 4, 0);   // VMEM reads (k+1)
        __builtin_amdgcn_sched_group_barrier(0x002, 28, 0);  // VALU (consume k)
    }
    float v0 = w00 * L00.x + w10 * L10.x + w01 * L01.x + w11 * L11.x;
    float v1 = w00 * L00.y + w10 * L10.y + w01 * L01.y + w11 * L11.y;
    float v2 = w00 * L00.z + w10 * L10.z + w01 * L01.z + w11 * L11.z;
    float v3 = w00 * L00.w + w10 * L10.w + w01 * L01.w + w11 * L11.w;
    sums[0] = __fadd_rn(sums[0], __fmul_rn(v0, m));
    sums[1] = __fadd_rn(sums[1], __fmul_rn(v1, m));
    sums[2] = __fadd_rn(sums[2], __fmul_rn(v2, m));
    sums[3] = __fadd_rn(sums[3], __fmul_rn(v3, m));
}

// ---------------- forward projection + ratio, fused ----------------
// block (256,2): x = radial bin r, y = t-half; grid (phi, quad).
__global__ __launch_bounds__(512, 2)
void project_ratio(const float* __restrict__ P, const float* __restrict__ PT,
                   const float* __restrict__ data,
                   const float* __restrict__ contam, const float* __restrict__ mult,
                   const float* __restrict__ cosb, const float* __restrict__ sinb,
                   const float* __restrict__ rvb, float* __restrict__ zt) {
    int phi = blockIdx.x;
    int qd = blockIdx.y;
    int i0 = qd * 4;
    int r = threadIdx.x;
    int half = threadIdx.y;
    bool active = (r < NUM_RAD);

    __shared__ float part[4][256];

    float sums[4] = {0.f, 0.f, 0.f, 0.f};
    float c = cosb[phi], sp = sinb[phi];

    bool useT = fabsf(sp) > fabsf(c);
    const float* basep = (useT ? PT : P) + qd * QSTRIDE;

    if (active) {
        float rv = rvb[r];
        float A = __fmul_rn(rv, -sp);   // RV * (-s)
        float B = __fmul_rn(rv, c);     // RV * c

        // conservative valid-t window
        float tlo = -350.f, thi = 350.f;
        bool empty = false;
        if (fabsf(c) > 1e-6f) {
            float a0 = (-199.f - A) / c, b0 = (199.f - A) / c;
            tlo = fmaxf(tlo, fminf(a0, b0)); thi = fminf(thi, fmaxf(a0, b0));
        } else if (fabsf(A) > 199.5f) empty = true;
        if (fabsf(sp) > 1e-6f) {
            float a0 = (-199.f - B) / sp, b0 = (199.f - B) / sp;
            tlo = fmaxf(tlo, fminf(a0, b0)); thi = fminf(thi, fmaxf(a0, b0));
        } else if (fabsf(B) > 199.5f) empty = true;

        int klo = max(0, (int)floorf((tlo + 350.f) * 0.5f) - 1);
        int khi = min(NUM_T - 1, (int)ceilf((thi + 350.f) * 0.5f) + 1);

        if (!empty && klo <= khi) {
            int kmid = (klo + khi + 1) >> 1;
            int kbeg = half ? kmid : klo;
            int kend = half ? khi : (kmid - 1);
            if (kbeg <= kend) {
                if (useT) ray_loop<true>(basep, kbeg, kend, A, B, c, sp, sums);
                else      ray_loop<false>(basep, kbeg, kend, A, B, c, sp, sums);
            }
        }
    }

    if (half == 1) {
#pragma unroll
        for (int s = 0; s < 4; ++s) part[s][r] = sums[s];
    }
    __syncthreads();
    if (half == 0 && active) {
#pragma unroll
        for (int s = 0; s < 4; ++s) {
            float proj = __fmul_rn(__fadd_rn(sums[s], part[s][r]), 2.0f);  // * STEP
            int sl = i0 + s;
            int idx = (sl * NUM_PHI + phi) * NUM_RAD + r;
            float ex = __fadd_rn(__fmul_rn(mult[idx], proj), contam[idx]);
            float zval = __fmul_rn(mult[idx], __fdiv_rn(data[idx], ex));
            zt[(phi * NUM_RAD + r) * N0 + sl] = zval;
        }
    }
}

// ---------------- adjoint projection, gather form, loads-first ----------------
// grid (ceil(NPIX/256), 19): thread = pixel, blockIdx.y = phi-chunk (uniform).
// Per p: compute j-window base jb, issue all 16 zt float4 loads (imm offsets),
// THEN the ~250-instr weight block runs while loads are in flight, then FMAs.
// Rows jb..jb+3 are a provable superset of the support; out-of-support rows
// get tent weight exactly 0.
__global__ __launch_bounds__(256, 2)
void backproject(const float* __restrict__ zt, const float* __restrict__ cosb,
                 const float* __restrict__ sinb, const float* __restrict__ rvb,
                 float* __restrict__ bp) {
    int pix = blockIdx.x * 256 + threadIdx.x;
    if (pix >= NPIX) return;
    int pc = blockIdx.y;
    int i1 = pix / N2;
    int i2 = pix - i1 * N2;
    float X1 = 2.f * (float)i1 - 199.f;   // ORG1 + i1*VOX (exact)
    float X2 = 2.f * (float)i2 - 199.f;
    float i1f = (float)i1, i2f = (float)i2;
    float acc[N0];
#pragma unroll
    for (int i0 = 0; i0 < N0; ++i0) acc[i0] = 0.f;

    int p_end = pc * BP_CHUNK + BP_CHUNK;
    for (int p = pc * BP_CHUNK; p < p_end; ++p) {
        float c = cosb[p], sp = sinb[p];
        float tp = c * X1 + sp * X2;      // candidate location only
        float rp = c * X2 - sp * X1;
        int j0 = (int)floorf((rp + 200.f) * 0.555f);   // 222/400 == 0.555 exactly
        int jb = min(max(j0 - 1, 0), NUM_RAD - 4);
        float tc = (tp + 350.f) * 0.5f;
        int kc = (int)floorf(tc + 0.5f);

        // rv for the 4 rows first (weights wait on these, z-loads stay in flight)
        float rv4[4];
#pragma unroll
        for (int dj = 0; dj < 4; ++dj) rv4[dj] = rvb[jb + dj];

        // 16 float4 loads off one base, immediate offsets 0..240B
        const float4* zb = (const float4*)(zt + (p * NUM_RAD + jb) * N0);
        float4 Z[4][4];
#pragma unroll
        for (int dj = 0; dj < 4; ++dj) {
            Z[dj][0] = zb[dj * 4 + 0]; Z[dj][1] = zb[dj * 4 + 1];
            Z[dj][2] = zb[dj * 4 + 2]; Z[dj][3] = zb[dj * 4 + 3];
        }
        __builtin_amdgcn_sched_group_barrier(0x020, 20, 0);  // all loads first
        __builtin_amdgcn_sched_group_barrier(0x002, 280, 0); // then weight VALU

        float wv[4];
#pragma unroll
        for (int dj = 0; dj < 4; ++dj) {
            float rv = rv4[dj];
            float A = __fmul_rn(rv, -sp);
            float B = __fmul_rn(rv, c);
            float w = 0.f;
#pragma unroll
            for (int dk = 0; dk < 3; ++dk) {
                int k = kc - 1 + dk;
                bool kvalid = (k >= 0) & (k <= NUM_T - 1);
                float tv = (float)(2 * k - 350);
                // EXACT same op sequence as forward -> identical ix/iy/validity
                float ix = __fmul_rn(__fsub_rn(__fadd_rn(A, __fmul_rn(tv, c)), ORG1F), 0.5f);
                float iy = __fmul_rn(__fsub_rn(__fadd_rn(B, __fmul_rn(tv, sp)), ORG2F), 0.5f);
                bool valid = kvalid & (ix >= 0.f) & (ix <= 199.f) & (iy >= 0.f) & (iy <= 199.f);
                // tent form == reference's floor/select chain (Sterbenz-exact)
                float wx = fmaxf(0.f, __fsub_rn(1.f, fabsf(__fsub_rn(ix, i1f))));
                float wy = fmaxf(0.f, __fsub_rn(1.f, fabsf(__fsub_rn(iy, i2f))));
                w += valid ? __fmul_rn(wx, wy) : 0.f;
            }
            wv[dj] = w;
        }

#pragma unroll
        for (int dj = 0; dj < 4; ++dj) {
            float w = wv[dj];
            acc[0]  += w * Z[dj][0].x;  acc[1]  += w * Z[dj][0].y;
            acc[2]  += w * Z[dj][0].z;  acc[3]  += w * Z[dj][0].w;
            acc[4]  += w * Z[dj][1].x;  acc[5]  += w * Z[dj][1].y;
            acc[6]  += w * Z[dj][1].z;  acc[7]  += w * Z[dj][1].w;
            acc[8]  += w * Z[dj][2].x;  acc[9]  += w * Z[dj][2].y;
            acc[10] += w * Z[dj][2].z;  acc[11] += w * Z[dj][2].w;
            acc[12] += w * Z[dj][3].x;  acc[13] += w * Z[dj][3].y;
            acc[14] += w * Z[dj][3].z;  acc[15] += w * Z[dj][3].w;
        }
    }
#pragma unroll
    for (int i0 = 0; i0 < N0; ++i0)
        atomicAdd(&bp[i0 * NPIX + pix], acc[i0] * 2.0f);  // * STEP
}

extern "C" void kernel_launch(void* const* d_in, const int* in_sizes, int n_in,
                              void* d_out, int out_size, void* d_ws, size_t ws_size,
                              hipStream_t stream) {
    const float* x      = (const float*)d_in[0];
    const float* data   = (const float*)d_in[1];
    const float* contam = (const float*)d_in[2];
    const float* mult   = (const float*)d_in[3];
    const float* sens   = (const float*)d_in[4];
    float* out = (float*)d_out;

    float* W    = (float*)d_ws;
    float* s    = W;                        // 640000 (smoothed; later reused as bp)
    float* tmp  = W + NVOX;                 // 640000
    float* bp2  = W + 2 * NVOX;             // 640000
    float* zt   = W + 3 * NVOX;             // 677920
    float* P    = W + 3 * NVOX + NSINO;     // 646416
    float* PT   = P + 4 * QSTRIDE;          // 646416
    float* cosb = PT + 4 * QSTRIDE;
    float* sinb = cosb + NUM_PHI;
    float* rvb  = sinb + NUM_PHI;
    float* gwb  = rvb + NUM_RAD;

    hipLaunchKernelGGL(init_consts, dim3(1), dim3(256), 0, stream, cosb, sinb, rvb, gwb);

    // gauss3 forward: x -> s (axis0), s -> tmp (axis1), tmp -> {P, PT} (axis2 quad dual-store)
    int nb = (NVOX + 255) / 256;
    hipLaunchKernelGGL(smooth_fwd, dim3(nb), dim3(256), 0, stream, x,   s,   gwb, N0, NPIX);
    hipLaunchKernelGGL(smooth_fwd, dim3(nb), dim3(256), 0, stream, s,   tmp, gwb, N1, N2);
    hipLaunchKernelGGL(smooth_fwd2_quad, dim3(nb), dim3(256), 0, stream, tmp, P, PT, gwb);

    // forward project + ratio (writes zt): 4 slices/thread via float4, 2 t-halves/block
    hipLaunchKernelGGL(project_ratio, dim3(NUM_PHI, N0 / 4), dim3(256, 2), 0, stream,
                       P, PT, data, contam, mult, cosb, sinb, rvb, zt);

    // backproject (gather) into bp (reuse s)
    float* bp = s;
    hipMemsetAsync(bp, 0, NVOX * sizeof(float), stream);
    int nbp = (NPIX + 255) / 256;
    hipLaunchKernelGGL(backproject, dim3(nbp, BP_NCH), dim3(256), 0, stream,
                       zt, cosb, sinb, rvb, bp);

    // gauss3 adjoint: bp -> tmp (axis2^T), tmp -> bp2 (axis1^T), bp2 -> out (axis0^T fused final)
    hipLaunchKernelGGL(smooth_adj, dim3(nb), dim3(256), 0, stream, bp,  tmp, gwb, N2, 1);
    hipLaunchKernelGGL(smooth_adj, dim3(nb), dim3(256), 0, stream, tmp, bp2, gwb, N1, N2);
    hipLaunchKernelGGL(smooth_adj0_final, dim3(nb), dim3(256), 0, stream, bp2, x, sens, gwb, out);
}

// Round 10
// 337.231 us; speedup vs baseline: 1.1070x; 1.0318x over previous
//
#include <hip/hip_runtime.h>
#include <math.h>

#define N0 16
#define N1 200
#define N2 200
#define NPIX (N1 * N2)            // 40000
#define NVOX (N0 * NPIX)          // 640000
#define NUM_RAD 223
#define NUM_PHI 190
#define NUM_T 351
#define NSINO (N0 * NUM_PHI * NUM_RAD)  // 677920
#define ORG1F (-199.0f)
#define ORG2F (-199.0f)
#define QSTRIDE (201 * 201 * 4)   // padded quad-interleaved slice group
#define BP_CHUNK 10
#define BP_NCH 19                 // 190 = 19 * 10

// ---------------- constants: replicate numpy linspace / cos / gaussian ----------------
__global__ void init_consts(float* __restrict__ cosb, float* __restrict__ sinb,
                            float* __restrict__ rvb, float* __restrict__ gwb) {
    int t = threadIdx.x;
    const double PI = 3.14159265358979311599796346854418516159;
    if (t < NUM_PHI) {
        double step = PI / 190.0;             // np.linspace(0, pi, 190, endpoint=False)
        float phif = (float)((double)t * step);
        cosb[t] = (float)cos((double)phif);   // np.cos on float32 input
        sinb[t] = (float)sin((double)phif);
    }
    if (t < NUM_RAD) {
        double step = 400.0 / 222.0;          // np.linspace(-200, 200, 223)
        float rv = (float)(-200.0 + (double)t * step);
        if (t == NUM_RAD - 1) rv = 200.0f;    // linspace endpoint fixup
        rvb[t] = rv;
    }
    if (t == 0) {
        double sig = 4.5 / (2.35 * 2.0);
        double g[9], ssum = 0.0;
        for (int k = 0; k < 9; ++k) { double d = (double)(k - 4) / sig; g[k] = exp(-0.5 * d * d); ssum += g[k]; }
        for (int k = 0; k < 9; ++k) gwb[k] = (float)(g[k] / ssum);
    }
}

// ---------------- separable gaussian, forward (symmetric pad) ----------------
__global__ void smooth_fwd(const float* __restrict__ in, float* __restrict__ out,
                           const float* __restrict__ gwb, int n, int stride) {
    int e = blockIdx.x * 256 + threadIdx.x;
    if (e >= NVOX) return;
    int a = (e / stride) % n;
    int base = e - a * stride;
    float sum = 0.f;
#pragma unroll
    for (int k = 0; k < 9; ++k) {
        int q = a + k - 4;
        q = (q < 0) ? (-1 - q) : ((q >= n) ? (2 * n - 1 - q) : q);
        sum = __fadd_rn(sum, __fmul_rn(gwb[k], in[base + q * stride]));
    }
    out[e] = sum;
}

// axis-2 pass writing quad-interleaved padded layouts:
//   P [q][i1][i2][s]  and  PT[q][i2][i1][s],  201x201 with edge replication.
__global__ void smooth_fwd2_quad(const float* __restrict__ in, float* __restrict__ P,
                                 float* __restrict__ PT, const float* __restrict__ gwb) {
    int e = blockIdx.x * 256 + threadIdx.x;
    if (e >= NVOX) return;
    int i2 = e % N2;
    int base = e - i2;
    float sum = 0.f;
#pragma unroll
    for (int k = 0; k < 9; ++k) {
        int q = i2 + k - 4;
        q = (q < 0) ? (-1 - q) : ((q >= N2) ? (2 * N2 - 1 - q) : q);
        sum = __fadd_rn(sum, __fmul_rn(gwb[k], in[base + q]));
    }
    int i0 = e / NPIX;
    int rem = e - i0 * NPIX;
    int i1 = rem / N2;
    int qd = i0 >> 2, s = i0 & 3;
    float* Pq  = P  + qd * QSTRIDE;
    float* PTq = PT + qd * QSTRIDE;
    bool e1 = (i1 == 199), e2 = (i2 == 199);
    Pq[(i1 * 201 + i2) * 4 + s] = sum;
    if (e2) Pq[(i1 * 201 + 200) * 4 + s] = sum;
    if (e1) Pq[(200 * 201 + i2) * 4 + s] = sum;
    if (e1 && e2) Pq[(200 * 201 + 200) * 4 + s] = sum;
    PTq[(i2 * 201 + i1) * 4 + s] = sum;
    if (e1) PTq[(i2 * 201 + 200) * 4 + s] = sum;
    if (e2) PTq[(200 * 201 + i1) * 4 + s] = sum;
    if (e1 && e2) PTq[(200 * 201 + 200) * 4 + s] = sum;
}

// ---------------- separable gaussian, adjoint (pad-transpose fold) ----------------
__device__ __forceinline__ float adj_u(const float* __restrict__ in, const float* __restrict__ gwb,
                                       int base, int stride, int n, int j) {
    float r = 0.f;
#pragma unroll
    for (int k = 0; k < 9; ++k) {
        int i = j - k;
        if (i >= 0 && i < n) r = __fadd_rn(r, __fmul_rn(gwb[k], in[base + i * stride]));
    }
    return r;
}

__global__ void smooth_adj(const float* __restrict__ in, float* __restrict__ out,
                           const float* __restrict__ gwb, int n, int stride) {
    int e = blockIdx.x * 256 + threadIdx.x;
    if (e >= NVOX) return;
    int a = (e / stride) % n;
    int base = e - a * stride;
    float v = adj_u(in, gwb, base, stride, n, a + 4);
    if (a < 4)      v = __fadd_rn(v, adj_u(in, gwb, base, stride, n, 3 - a));
    if (a >= n - 4) v = __fadd_rn(v, adj_u(in, gwb, base, stride, n, 2 * n + 3 - a));
    out[e] = v;
}

// final axis-0 adjoint pass fused with  out = x * v / sens
__global__ void smooth_adj0_final(const float* __restrict__ in, const float* __restrict__ x,
                                  const float* __restrict__ sens, const float* __restrict__ gwb,
                                  float* __restrict__ out) {
    int e = blockIdx.x * 256 + threadIdx.x;
    if (e >= NVOX) return;
    int a = e / NPIX;
    int base = e - a * NPIX;
    float v = adj_u(in, gwb, base, NPIX, N0, a + 4);
    if (a < 4)  v = __fadd_rn(v, adj_u(in, gwb, base, NPIX, N0, 3 - a));
    if (a >= 12) v = __fadd_rn(v, adj_u(in, gwb, base, NPIX, N0, 35 - a));
    out[e] = __fdiv_rn(__fmul_rn(x[e], v), sens[e]);
}

// geometry for one t-sample; USET selects row/col roles at compile time.
template<bool USET>
__device__ __forceinline__ void geom(int K, float A, float B, float c, float sp,
                                     float& W00, float& W10, float& W01, float& W11,
                                     float& M, int& O) {
    float tv = (float)(2 * K - 350);
    float ix = __fmul_rn(__fsub_rn(__fadd_rn(A, __fmul_rn(tv, c)), ORG1F), 0.5f);
    float iy = __fmul_rn(__fsub_rn(__fadd_rn(B, __fmul_rn(tv, sp)), ORG2F), 0.5f);
    bool valid = (ix >= 0.f && ix <= 199.f && iy >= 0.f && iy <= 199.f);
    float fx = floorf(ix), fy = floorf(iy);
    int ii = (int)fx, jj = (int)fy;
    float fi = ix - fx, fj = iy - fy;
    int ii0 = min(max(ii, 0), 199), jj0 = min(max(jj, 0), 199);
    int rowi = USET ? jj0 : ii0;
    int coli = USET ? ii0 : jj0;
    O = rowi * 804 + coli * 4;
    W00 = (1.f - fi) * (1.f - fj); W10 = fi * (1.f - fj);
    W01 = (1.f - fi) * fj;         W11 = fi * fj;
    M = valid ? 1.f : 0.f;
}

// k-loop over one t-range, 1-ahead software pipeline pinned with sched_group_barrier.
template<bool USET>
__device__ __forceinline__ void ray_loop(const float* __restrict__ basep,
                                         int kbeg, int kend, float A, float B,
                                         float c, float sp, float sums[4]) {
    constexpr int O10 = USET ? 4 : 804;   // ii+1 step (floats)
    constexpr int O01 = USET ? 804 : 4;   // jj+1 step (floats)
    float w00, w10, w01, w11, m;
    int o;
    geom<USET>(kbeg, A, B, c, sp, w00, w10, w01, w11, m, o);
    float4 L00 = *(const float4*)(basep + o);
    float4 L10 = *(const float4*)(basep + o + O10);
    float4 L01 = *(const float4*)(basep + o + O01);
    float4 L11 = *(const float4*)(basep + o + 808);
    for (int k = kbeg; k < kend; ++k) {
        float nw00, nw10, nw01, nw11, nm;
        int no;
        geom<USET>(k + 1, A, B, c, sp, nw00, nw10, nw01, nw11, nm, no);
        float4 N00 = *(const float4*)(basep + no);
        float4 N10 = *(const float4*)(basep + no + O10);
        float4 N01 = *(const float4*)(basep + no + O01);
        float4 N11 = *(const float4*)(basep + no + 808);
        float v0 = w00 * L00.x + w10 * L10.x + w01 * L01.x + w11 * L11.x;
        float v1 = w00 * L00.y + w10 * L10.y + w01 * L01.y + w11 * L11.y;
        float v2 = w00 * L00.z + w10 * L10.z + w01 * L01.z + w11 * L11.z;
        float v3 = w00 * L00.w + w10 * L10.w + w01 * L01.w + w11 * L11.w;
        sums[0] = __fadd_rn(sums[0], __fmul_rn(v0, m));
        sums[1] = __fadd_rn(sums[1], __fmul_rn(v1, m));
        sums[2] = __fadd_rn(sums[2], __fmul_rn(v2, m));
        sums[3] = __fadd_rn(sums[3], __fmul_rn(v3, m));
        w00 = nw00; w10 = nw10; w01 = nw01; w11 = nw11; m = nm;
        L00 = N00; L10 = N10; L01 = N01; L11 = N11;
        // pin: geometry VALU for k+1, then its 4 loads, then consume of k
        __builtin_amdgcn_sched_group_barrier(0x002, 28, 0);  // VALU (geom k+1)
        __builtin_amdgcn_sched_group_barrier(0x020, 4, 0);   // VMEM reads (k+1)
        __builtin_amdgcn_sched_group_barrier(0x002, 28, 0);  // VALU (consume k)
    }
    float v0 = w00 * L00.x + w10 * L10.x + w01 * L01.x + w11 * L11.x;
    float v1 = w00 * L00.y + w10 * L10.y + w01 * L01.y + w11 * L11.y;
    float v2 = w00 * L00.z + w10 * L10.z + w01 * L01.z + w11 * L11.z;
    float v3 = w00 * L00.w + w10 * L10.w + w01 * L01.w + w11 * L11.w;
    sums[0] = __fadd_rn(sums[0], __fmul_rn(v0, m));
    sums[1] = __fadd_rn(sums[1], __fmul_rn(v1, m));
    sums[2] = __fadd_rn(sums[2], __fmul_rn(v2, m));
    sums[3] = __fadd_rn(sums[3], __fmul_rn(v3, m));
}

// ---------------- forward projection + ratio, fused ----------------
// 1D grid of 760 blocks: quad = b & 3, phi = b >> 2. blockIdx -> XCD is
// round-robin (% 8), so each XCD only ever touches ONE quad's P/PT slabs
// (1.29 MB << 4 MB L2) -> image stays L2-resident, no cross-quad thrash.
// block (256,2): x = radial bin r, y = t-half.
__global__ __launch_bounds__(512, 2)
void project_ratio(const float* __restrict__ P, const float* __restrict__ PT,
                   const float* __restrict__ data,
                   const float* __restrict__ contam, const float* __restrict__ mult,
                   const float* __restrict__ cosb, const float* __restrict__ sinb,
                   const float* __restrict__ rvb, float* __restrict__ zt) {
    int b = blockIdx.x;
    int qd = b & 3;               // XCD-pinned quad
    int phi = b >> 2;
    int i0 = qd * 4;
    int r = threadIdx.x;
    int half = threadIdx.y;
    bool active = (r < NUM_RAD);

    __shared__ float part[4][256];

    float sums[4] = {0.f, 0.f, 0.f, 0.f};
    float c = cosb[phi], sp = sinb[phi];

    bool useT = fabsf(sp) > fabsf(c);
    const float* basep = (useT ? PT : P) + qd * QSTRIDE;

    if (active) {
        float rv = rvb[r];
        float A = __fmul_rn(rv, -sp);   // RV * (-s)
        float B = __fmul_rn(rv, c);     // RV * c

        // conservative valid-t window
        float tlo = -350.f, thi = 350.f;
        bool empty = false;
        if (fabsf(c) > 1e-6f) {
            float a0 = (-199.f - A) / c, b0 = (199.f - A) / c;
            tlo = fmaxf(tlo, fminf(a0, b0)); thi = fminf(thi, fmaxf(a0, b0));
        } else if (fabsf(A) > 199.5f) empty = true;
        if (fabsf(sp) > 1e-6f) {
            float a0 = (-199.f - B) / sp, b0 = (199.f - B) / sp;
            tlo = fmaxf(tlo, fminf(a0, b0)); thi = fminf(thi, fmaxf(a0, b0));
        } else if (fabsf(B) > 199.5f) empty = true;

        int klo = max(0, (int)floorf((tlo + 350.f) * 0.5f) - 1);
        int khi = min(NUM_T - 1, (int)ceilf((thi + 350.f) * 0.5f) + 1);

        if (!empty && klo <= khi) {
            int kmid = (klo + khi + 1) >> 1;
            int kbeg = half ? kmid : klo;
            int kend = half ? khi : (kmid - 1);
            if (kbeg <= kend) {
                if (useT) ray_loop<true>(basep, kbeg, kend, A, B, c, sp, sums);
                else      ray_loop<false>(basep, kbeg, kend, A, B, c, sp, sums);
            }
        }
    }

    if (half == 1) {
#pragma unroll
        for (int s = 0; s < 4; ++s) part[s][r] = sums[s];
    }
    __syncthreads();
    if (half == 0 && active) {
#pragma unroll
        for (int s = 0; s < 4; ++s) {
            float proj = __fmul_rn(__fadd_rn(sums[s], part[s][r]), 2.0f);  // * STEP
            int sl = i0 + s;
            int idx = (sl * NUM_PHI + phi) * NUM_RAD + r;
            float ex = __fadd_rn(__fmul_rn(mult[idx], proj), contam[idx]);
            float zval = __fmul_rn(mult[idx], __fdiv_rn(data[idx], ex));
            zt[(phi * NUM_RAD + r) * N0 + sl] = zval;
        }
    }
}

// ---------------- adjoint projection, gather form, loads-first ----------------
// grid (ceil(NPIX/256), 19): thread = pixel, blockIdx.y = phi-chunk (uniform).
// Per p: compute j-window base jb, issue all 16 zt float4 loads (imm offsets),
// THEN the ~250-instr weight block runs while loads are in flight, then FMAs.
// Rows jb..jb+3 are a provable superset of the support; out-of-support rows
// get tent weight exactly 0.
__global__ __launch_bounds__(256, 2)
void backproject(const float* __restrict__ zt, const float* __restrict__ cosb,
                 const float* __restrict__ sinb, const float* __restrict__ rvb,
                 float* __restrict__ bp) {
    int pix = blockIdx.x * 256 + threadIdx.x;
    if (pix >= NPIX) return;
    int pc = blockIdx.y;
    int i1 = pix / N2;
    int i2 = pix - i1 * N2;
    float X1 = 2.f * (float)i1 - 199.f;   // ORG1 + i1*VOX (exact)
    float X2 = 2.f * (float)i2 - 199.f;
    float i1f = (float)i1, i2f = (float)i2;
    float acc[N0];
#pragma unroll
    for (int i0 = 0; i0 < N0; ++i0) acc[i0] = 0.f;

    int p_end = pc * BP_CHUNK + BP_CHUNK;
    for (int p = pc * BP_CHUNK; p < p_end; ++p) {
        float c = cosb[p], sp = sinb[p];
        float tp = c * X1 + sp * X2;      // candidate location only
        float rp = c * X2 - sp * X1;
        int j0 = (int)floorf((rp + 200.f) * 0.555f);   // 222/400 == 0.555 exactly
        int jb = min(max(j0 - 1, 0), NUM_RAD - 4);
        float tc = (tp + 350.f) * 0.5f;
        int kc = (int)floorf(tc + 0.5f);

        // rv for the 4 rows first (weights wait on these, z-loads stay in flight)
        float rv4[4];
#pragma unroll
        for (int dj = 0; dj < 4; ++dj) rv4[dj] = rvb[jb + dj];

        // 16 float4 loads off one base, immediate offsets 0..240B
        const float4* zb = (const float4*)(zt + (p * NUM_RAD + jb) * N0);
        float4 Z[4][4];
#pragma unroll
        for (int dj = 0; dj < 4; ++dj) {
            Z[dj][0] = zb[dj * 4 + 0]; Z[dj][1] = zb[dj * 4 + 1];
            Z[dj][2] = zb[dj * 4 + 2]; Z[dj][3] = zb[dj * 4 + 3];
        }
        __builtin_amdgcn_sched_group_barrier(0x020, 20, 0);  // all loads first
        __builtin_amdgcn_sched_group_barrier(0x002, 280, 0); // then weight VALU

        float wv[4];
#pragma unroll
        for (int dj = 0; dj < 4; ++dj) {
            float rv = rv4[dj];
            float A = __fmul_rn(rv, -sp);
            float B = __fmul_rn(rv, c);
            float w = 0.f;
#pragma unroll
            for (int dk = 0; dk < 3; ++dk) {
                int k = kc - 1 + dk;
                bool kvalid = (k >= 0) & (k <= NUM_T - 1);
                float tv = (float)(2 * k - 350);
                // EXACT same op sequence as forward -> identical ix/iy/validity
                float ix = __fmul_rn(__fsub_rn(__fadd_rn(A, __fmul_rn(tv, c)), ORG1F), 0.5f);
                float iy = __fmul_rn(__fsub_rn(__fadd_rn(B, __fmul_rn(tv, sp)), ORG2F), 0.5f);
                bool valid = kvalid & (ix >= 0.f) & (ix <= 199.f) & (iy >= 0.f) & (iy <= 199.f);
                // tent form == reference's floor/select chain (Sterbenz-exact)
                float wx = fmaxf(0.f, __fsub_rn(1.f, fabsf(__fsub_rn(ix, i1f))));
                float wy = fmaxf(0.f, __fsub_rn(1.f, fabsf(__fsub_rn(iy, i2f))));
                w += valid ? __fmul_rn(wx, wy) : 0.f;
            }
            wv[dj] = w;
        }

#pragma unroll
        for (int dj = 0; dj < 4; ++dj) {
            float w = wv[dj];
            acc[0]  += w * Z[dj][0].x;  acc[1]  += w * Z[dj][0].y;
            acc[2]  += w * Z[dj][0].z;  acc[3]  += w * Z[dj][0].w;
            acc[4]  += w * Z[dj][1].x;  acc[5]  += w * Z[dj][1].y;
            acc[6]  += w * Z[dj][1].z;  acc[7]  += w * Z[dj][1].w;
            acc[8]  += w * Z[dj][2].x;  acc[9]  += w * Z[dj][2].y;
            acc[10] += w * Z[dj][2].z;  acc[11] += w * Z[dj][2].w;
            acc[12] += w * Z[dj][3].x;  acc[13] += w * Z[dj][3].y;
            acc[14] += w * Z[dj][3].z;  acc[15] += w * Z[dj][3].w;
        }
    }
#pragma unroll
    for (int i0 = 0; i0 < N0; ++i0)
        atomicAdd(&bp[i0 * NPIX + pix], acc[i0] * 2.0f);  // * STEP
}

extern "C" void kernel_launch(void* const* d_in, const int* in_sizes, int n_in,
                              void* d_out, int out_size, void* d_ws, size_t ws_size,
                              hipStream_t stream) {
    const float* x      = (const float*)d_in[0];
    const float* data   = (const float*)d_in[1];
    const float* contam = (const float*)d_in[2];
    const float* mult   = (const float*)d_in[3];
    const float* sens   = (const float*)d_in[4];
    float* out = (float*)d_out;

    float* W    = (float*)d_ws;
    float* s    = W;                        // 640000 (smoothed; later reused as bp)
    float* tmp  = W + NVOX;                 // 640000
    float* bp2  = W + 2 * NVOX;             // 640000
    float* zt   = W + 3 * NVOX;             // 677920
    float* P    = W + 3 * NVOX + NSINO;     // 646416
    float* PT   = P + 4 * QSTRIDE;          // 646416
    float* cosb = PT + 4 * QSTRIDE;
    float* sinb = cosb + NUM_PHI;
    float* rvb  = sinb + NUM_PHI;
    float* gwb  = rvb + NUM_RAD;

    hipLaunchKernelGGL(init_consts, dim3(1), dim3(256), 0, stream, cosb, sinb, rvb, gwb);

    // gauss3 forward: x -> s (axis0), s -> tmp (axis1), tmp -> {P, PT} (axis2 quad dual-store)
    int nb = (NVOX + 255) / 256;
    hipLaunchKernelGGL(smooth_fwd, dim3(nb), dim3(256), 0, stream, x,   s,   gwb, N0, NPIX);
    hipLaunchKernelGGL(smooth_fwd, dim3(nb), dim3(256), 0, stream, s,   tmp, gwb, N1, N2);
    hipLaunchKernelGGL(smooth_fwd2_quad, dim3(nb), dim3(256), 0, stream, tmp, P, PT, gwb);

    // forward project + ratio (writes zt): 1D grid, quad = b&3 (XCD-pinned)
    hipLaunchKernelGGL(project_ratio, dim3(NUM_PHI * (N0 / 4)), dim3(256, 2), 0, stream,
                       P, PT, data, contam, mult, cosb, sinb, rvb, zt);

    // backproject (gather) into bp (reuse s)
    float* bp = s;
    hipMemsetAsync(bp, 0, NVOX * sizeof(float), stream);
    int nbp = (NPIX + 255) / 256;
    hipLaunchKernelGGL(backproject, dim3(nbp, BP_NCH), dim3(256), 0, stream,
                       zt, cosb, sinb, rvb, bp);

    // gauss3 adjoint: bp -> tmp (axis2^T), tmp -> bp2 (axis1^T), bp2 -> out (axis0^T fused final)
    hipLaunchKernelGGL(smooth_adj, dim3(nb), dim3(256), 0, stream, bp,  tmp, gwb, N2, 1);
    hipLaunchKernelGGL(smooth_adj, dim3(nb), dim3(256), 0, stream, tmp, bp2, gwb, N1, N2);
    hipLaunchKernelGGL(smooth_adj0_final, dim3(nb), dim3(256), 0, stream, bp2, x, sens, gwb, out);
}

// Round 11
// 337.128 us; speedup vs baseline: 1.1073x; 1.0003x over previous
//
#include <hip/hip_runtime.h>
#include <math.h>

#define N0 16
#define N1 200
#define N2 200
#define NPIX (N1 * N2)            // 40000
#define NVOX (N0 * NPIX)          // 640000
#define NUM_RAD 223
#define NUM_PHI 190
#define NUM_T 351
#define NSINO (N0 * NUM_PHI * NUM_RAD)  // 677920
#define ORG1F (-199.0f)
#define ORG2F (-199.0f)
// padded quad-interleaved layout: 208x208 px (+4 border each side), 2 slack rows
#define PITCH 832                 // 208 cols * 4 slices (floats per row)
#define QS2 (832 * 210)           // 174720 floats per quad slab
#define BASEOFF (4 * 832 + 16)    // (+4 rows, +4 cols) origin shift, floats
#define BP_CHUNK 10
#define BP_NCH 19                 // 190 = 19 * 10

// ---------------- constants: replicate numpy linspace / cos / gaussian ----------------
__global__ void init_consts(float* __restrict__ cosb, float* __restrict__ sinb,
                            float* __restrict__ rvb, float* __restrict__ gwb) {
    int t = threadIdx.x;
    const double PI = 3.14159265358979311599796346854418516159;
    if (t < NUM_PHI) {
        double step = PI / 190.0;             // np.linspace(0, pi, 190, endpoint=False)
        float phif = (float)((double)t * step);
        cosb[t] = (float)cos((double)phif);   // np.cos on float32 input
        sinb[t] = (float)sin((double)phif);
    }
    if (t < NUM_RAD) {
        double step = 400.0 / 222.0;          // np.linspace(-200, 200, 223)
        float rv = (float)(-200.0 + (double)t * step);
        if (t == NUM_RAD - 1) rv = 200.0f;    // linspace endpoint fixup
        rvb[t] = rv;
    }
    if (t == 0) {
        double sig = 4.5 / (2.35 * 2.0);
        double g[9], ssum = 0.0;
        for (int k = 0; k < 9; ++k) { double d = (double)(k - 4) / sig; g[k] = exp(-0.5 * d * d); ssum += g[k]; }
        for (int k = 0; k < 9; ++k) gwb[k] = (float)(g[k] / ssum);
    }
}

// ---------------- separable gaussian, forward (symmetric pad) ----------------
__global__ void smooth_fwd(const float* __restrict__ in, float* __restrict__ out,
                           const float* __restrict__ gwb, int n, int stride) {
    int e = blockIdx.x * 256 + threadIdx.x;
    if (e >= NVOX) return;
    int a = (e / stride) % n;
    int base = e - a * stride;
    float sum = 0.f;
#pragma unroll
    for (int k = 0; k < 9; ++k) {
        int q = a + k - 4;
        q = (q < 0) ? (-1 - q) : ((q >= n) ? (2 * n - 1 - q) : q);
        sum = __fadd_rn(sum, __fmul_rn(gwb[k], in[base + q * stride]));
    }
    out[e] = sum;
}

// axis-2 pass writing padded quad-interleaved layouts:
//   P [q][i1+4][i2+4][s] and PT[q][i2+4][i1+4][s], pitch 832 floats.
// Borders are NEVER initialized: they are only read with weights forced to
// exactly 0 (0xAA poison is a finite float, 0*x == 0).
__global__ void smooth_fwd2_quad(const float* __restrict__ in, float* __restrict__ P,
                                 float* __restrict__ PT, const float* __restrict__ gwb) {
    int e = blockIdx.x * 256 + threadIdx.x;
    if (e >= NVOX) return;
    int i2 = e % N2;
    int base = e - i2;
    float sum = 0.f;
#pragma unroll
    for (int k = 0; k < 9; ++k) {
        int q = i2 + k - 4;
        q = (q < 0) ? (-1 - q) : ((q >= N2) ? (2 * N2 - 1 - q) : q);
        sum = __fadd_rn(sum, __fmul_rn(gwb[k], in[base + q]));
    }
    int i0 = e / NPIX;
    int rem = e - i0 * NPIX;
    int i1 = rem / N2;
    int qd = i0 >> 2, s = i0 & 3;
    P [qd * QS2 + BASEOFF + i1 * PITCH + i2 * 4 + s] = sum;
    PT[qd * QS2 + BASEOFF + i2 * PITCH + i1 * 4 + s] = sum;
}

// ---------------- separable gaussian, adjoint (pad-transpose fold) ----------------
__device__ __forceinline__ float adj_u(const float* __restrict__ in, const float* __restrict__ gwb,
                                       int base, int stride, int n, int j) {
    float r = 0.f;
#pragma unroll
    for (int k = 0; k < 9; ++k) {
        int i = j - k;
        if (i >= 0 && i < n) r = __fadd_rn(r, __fmul_rn(gwb[k], in[base + i * stride]));
    }
    return r;
}

__global__ void smooth_adj(const float* __restrict__ in, float* __restrict__ out,
                           const float* __restrict__ gwb, int n, int stride) {
    int e = blockIdx.x * 256 + threadIdx.x;
    if (e >= NVOX) return;
    int a = (e / stride) % n;
    int base = e - a * stride;
    float v = adj_u(in, gwb, base, stride, n, a + 4);
    if (a < 4)      v = __fadd_rn(v, adj_u(in, gwb, base, stride, n, 3 - a));
    if (a >= n - 4) v = __fadd_rn(v, adj_u(in, gwb, base, stride, n, 2 * n + 3 - a));
    out[e] = v;
}

// final axis-0 adjoint pass fused with  out = x * v / sens
__global__ void smooth_adj0_final(const float* __restrict__ in, const float* __restrict__ x,
                                  const float* __restrict__ sens, const float* __restrict__ gwb,
                                  float* __restrict__ out) {
    int e = blockIdx.x * 256 + threadIdx.x;
    if (e >= NVOX) return;
    int a = e / NPIX;
    int base = e - a * NPIX;
    float v = adj_u(in, gwb, base, NPIX, N0, a + 4);
    if (a < 4)  v = __fadd_rn(v, adj_u(in, gwb, base, NPIX, N0, 3 - a));
    if (a >= 12) v = __fadd_rn(v, adj_u(in, gwb, base, NPIX, N0, 35 - a));
    out[e] = __fdiv_rn(__fmul_rn(x[e], v), sens[e]);
}

// lean geometry: ix = fma(tv, c/2, Ah), weights pre-masked to exactly 0 when
// invalid (so poison borders contribute exactly 0).
template<bool USET>
__device__ __forceinline__ void geom2(float tv, float ch, float sh, float Ah, float Bh,
                                      float& w00, float& w10, float& w01, float& w11,
                                      int& o) {
    float ix = fmaf(tv, ch, Ah);
    float iy = fmaf(tv, sh, Bh);
    bool valid = (ix >= 0.f) & (ix <= 199.f) & (iy >= 0.f) & (iy <= 199.f);
    float fx = floorf(ix), fy = floorf(iy);
    int ii = (int)fx, jj = (int)fy;       // may be negative: pad covers [-4,203]
    float fi = ix - fx, fj = iy - fy;
    int rowi = USET ? jj : ii;
    int coli = USET ? ii : jj;
    o = rowi * PITCH + coli * 4;
    float gi = 1.f - fi, gj = 1.f - fj;
    w00 = valid ? gi * gj : 0.f;
    w10 = valid ? fi * gj : 0.f;
    w01 = valid ? gi * fj : 0.f;
    w11 = valid ? fi * fj : 0.f;
}

// k-loop, 1-ahead software pipeline pinned with sched_group_barrier.
template<bool USET>
__device__ __forceinline__ void ray_loop(const float* __restrict__ basep,
                                         int kbeg, int kend, float ch, float sh,
                                         float Ah, float Bh, float sums[4]) {
    constexpr int O10 = USET ? 4 : PITCH;   // ii+1 step (floats)
    constexpr int O01 = USET ? PITCH : 4;   // jj+1 step (floats)
    float tv = (float)(2 * kbeg - 350);
    float w00, w10, w01, w11;
    int o;
    geom2<USET>(tv, ch, sh, Ah, Bh, w00, w10, w01, w11, o);
    float4 L00 = *(const float4*)(basep + o);
    float4 L10 = *(const float4*)(basep + o + O10);
    float4 L01 = *(const float4*)(basep + o + O01);
    float4 L11 = *(const float4*)(basep + o + O10 + O01);
#pragma unroll 2
    for (int k = kbeg; k < kend; ++k) {
        tv += 2.0f;
        float nw00, nw10, nw01, nw11;
        int no;
        geom2<USET>(tv, ch, sh, Ah, Bh, nw00, nw10, nw01, nw11, no);
        float4 N00 = *(const float4*)(basep + no);
        float4 N10 = *(const float4*)(basep + no + O10);
        float4 N01 = *(const float4*)(basep + no + O01);
        float4 N11 = *(const float4*)(basep + no + O10 + O01);
        // consume current: direct FMA accumulate (mask already in weights)
        sums[0] = fmaf(w00, L00.x, sums[0]); sums[0] = fmaf(w10, L10.x, sums[0]);
        sums[0] = fmaf(w01, L01.x, sums[0]); sums[0] = fmaf(w11, L11.x, sums[0]);
        sums[1] = fmaf(w00, L00.y, sums[1]); sums[1] = fmaf(w10, L10.y, sums[1]);
        sums[1] = fmaf(w01, L01.y, sums[1]); sums[1] = fmaf(w11, L11.y, sums[1]);
        sums[2] = fmaf(w00, L00.z, sums[2]); sums[2] = fmaf(w10, L10.z, sums[2]);
        sums[2] = fmaf(w01, L01.z, sums[2]); sums[2] = fmaf(w11, L11.z, sums[2]);
        sums[3] = fmaf(w00, L00.w, sums[3]); sums[3] = fmaf(w10, L10.w, sums[3]);
        sums[3] = fmaf(w01, L01.w, sums[3]); sums[3] = fmaf(w11, L11.w, sums[3]);
        w00 = nw00; w10 = nw10; w01 = nw01; w11 = nw11;
        L00 = N00; L10 = N10; L01 = N01; L11 = N11;
        __builtin_amdgcn_sched_group_barrier(0x002, 24, 0);  // VALU (geom k+1)
        __builtin_amdgcn_sched_group_barrier(0x020, 4, 0);   // VMEM reads (k+1)
        __builtin_amdgcn_sched_group_barrier(0x002, 16, 0);  // VALU (consume k)
    }
    sums[0] = fmaf(w00, L00.x, sums[0]); sums[0] = fmaf(w10, L10.x, sums[0]);
    sums[0] = fmaf(w01, L01.x, sums[0]); sums[0] = fmaf(w11, L11.x, sums[0]);
    sums[1] = fmaf(w00, L00.y, sums[1]); sums[1] = fmaf(w10, L10.y, sums[1]);
    sums[1] = fmaf(w01, L01.y, sums[1]); sums[1] = fmaf(w11, L11.y, sums[1]);
    sums[2] = fmaf(w00, L00.z, sums[2]); sums[2] = fmaf(w10, L10.z, sums[2]);
    sums[2] = fmaf(w01, L01.z, sums[2]); sums[2] = fmaf(w11, L11.z, sums[2]);
    sums[3] = fmaf(w00, L00.w, sums[3]); sums[3] = fmaf(w10, L10.w, sums[3]);
    sums[3] = fmaf(w01, L01.w, sums[3]); sums[3] = fmaf(w11, L11.w, sums[3]);
}

// ---------------- forward projection + ratio, fused ----------------
// 1D grid of 760 blocks: quad = b & 3 (XCD-pinned), phi = b >> 2.
// block (256,2): x = radial bin r, y = t-half.
__global__ __launch_bounds__(512, 2)
void project_ratio(const float* __restrict__ P, const float* __restrict__ PT,
                   const float* __restrict__ data,
                   const float* __restrict__ contam, const float* __restrict__ mult,
                   const float* __restrict__ cosb, const float* __restrict__ sinb,
                   const float* __restrict__ rvb, float* __restrict__ zt) {
    int b = blockIdx.x;
    int qd = b & 3;               // XCD-pinned quad
    int phi = b >> 2;
    int i0 = qd * 4;
    int r = threadIdx.x;
    int half = threadIdx.y;
    bool active = (r < NUM_RAD);

    __shared__ float part[4][256];

    float sums[4] = {0.f, 0.f, 0.f, 0.f};
    float c = cosb[phi], sp = sinb[phi];
    float ch = c * 0.5f, sh = sp * 0.5f;   // exact halves

    bool useT = fabsf(sp) > fabsf(c);
    const float* basep = (useT ? PT : P) + qd * QS2 + BASEOFF;

    if (active) {
        float rv = rvb[r];
        float A = __fmul_rn(rv, -sp);   // RV * (-s)  (window calc)
        float B = __fmul_rn(rv, c);     // RV * c
        float Ah = fmaf(rv, -sh, 99.5f);  // (A + 199)/2 up to 1-2 ulp
        float Bh = fmaf(rv, ch, 99.5f);

        // conservative valid-t window
        float tlo = -350.f, thi = 350.f;
        bool empty = false;
        if (fabsf(c) > 1e-6f) {
            float a0 = (-199.f - A) / c, b0 = (199.f - A) / c;
            tlo = fmaxf(tlo, fminf(a0, b0)); thi = fminf(thi, fmaxf(a0, b0));
        } else if (fabsf(A) > 199.5f) empty = true;
        if (fabsf(sp) > 1e-6f) {
            float a0 = (-199.f - B) / sp, b0 = (199.f - B) / sp;
            tlo = fmaxf(tlo, fminf(a0, b0)); thi = fminf(thi, fmaxf(a0, b0));
        } else if (fabsf(B) > 199.5f) empty = true;

        int klo = max(0, (int)floorf((tlo + 350.f) * 0.5f) - 1);
        int khi = min(NUM_T - 1, (int)ceilf((thi + 350.f) * 0.5f) + 1);

        if (!empty && klo <= khi) {
            int kmid = (klo + khi + 1) >> 1;
            int kbeg = half ? kmid : klo;
            int kend = half ? khi : (kmid - 1);
            if (kbeg <= kend) {
                if (useT) ray_loop<true>(basep, kbeg, kend, ch, sh, Ah, Bh, sums);
                else      ray_loop<false>(basep, kbeg, kend, ch, sh, Ah, Bh, sums);
            }
        }
    }

    if (half == 1) {
#pragma unroll
        for (int s = 0; s < 4; ++s) part[s][r] = sums[s];
    }
    __syncthreads();
    if (half == 0 && active) {
#pragma unroll
        for (int s = 0; s < 4; ++s) {
            float proj = __fmul_rn(__fadd_rn(sums[s], part[s][r]), 2.0f);  // * STEP
            int sl = i0 + s;
            int idx = (sl * NUM_PHI + phi) * NUM_RAD + r;
            float ex = __fadd_rn(__fmul_rn(mult[idx], proj), contam[idx]);
            float zval = __fmul_rn(mult[idx], __fdiv_rn(data[idx], ex));
            zt[(phi * NUM_RAD + r) * N0 + sl] = zval;
        }
    }
}

// ---------------- adjoint projection, gather form, loads-first ----------------
// grid (ceil(NPIX/256), 19): thread = pixel, blockIdx.y = phi-chunk (uniform).
// k-candidates kc-1..kc+1 are ALWAYS in [0,350]: |tp| <= 199*sqrt(2) < 281
// -> tc in [34.3, 315.7] -> kc+-1 in [33, 317]. No k bounds check needed.
// ix separates as Px[j] + Qx[k] (1 add/sample).
__global__ __launch_bounds__(256, 2)
void backproject(const float* __restrict__ zt, const float* __restrict__ cosb,
                 const float* __restrict__ sinb, const float* __restrict__ rvb,
                 float* __restrict__ bp) {
    int pix = blockIdx.x * 256 + threadIdx.x;
    if (pix >= NPIX) return;
    int pc = blockIdx.y;
    int i1 = pix / N2;
    int i2 = pix - i1 * N2;
    float X1 = 2.f * (float)i1 - 199.f;   // ORG1 + i1*VOX (exact)
    float X2 = 2.f * (float)i2 - 199.f;
    float i1f = (float)i1, i2f = (float)i2;
    float acc[N0];
#pragma unroll
    for (int i0 = 0; i0 < N0; ++i0) acc[i0] = 0.f;

    int p_end = pc * BP_CHUNK + BP_CHUNK;
    for (int p = pc * BP_CHUNK; p < p_end; ++p) {
        float c = cosb[p], sp = sinb[p];
        float ch = c * 0.5f, sh = sp * 0.5f;
        float tp = c * X1 + sp * X2;
        float rp = c * X2 - sp * X1;
        int j0 = (int)floorf((rp + 200.f) * 0.555f);   // conservative bin
        int jb = min(max(j0 - 1, 0), NUM_RAD - 4);
        float tc = (tp + 350.f) * 0.5f;
        int kc = (int)floorf(tc + 0.5f);

        // row rv loads
        float rv4[4];
#pragma unroll
        for (int dj = 0; dj < 4; ++dj) rv4[dj] = rvb[jb + dj];

        // 16 float4 loads off one base, immediate offsets
        const float4* zb = (const float4*)(zt + (p * NUM_RAD + jb) * N0);
        float4 Z[4][4];
#pragma unroll
        for (int dj = 0; dj < 4; ++dj) {
            Z[dj][0] = zb[dj * 4 + 0]; Z[dj][1] = zb[dj * 4 + 1];
            Z[dj][2] = zb[dj * 4 + 2]; Z[dj][3] = zb[dj * 4 + 3];
        }
        __builtin_amdgcn_sched_group_barrier(0x020, 20, 0);  // all loads first
        __builtin_amdgcn_sched_group_barrier(0x002, 220, 0); // then weight VALU

        // separated geometry
        float tvc = (float)(2 * kc - 350);
        float Qx[3], Qy[3];
#pragma unroll
        for (int dk = 0; dk < 3; ++dk) {
            float tv = tvc + (float)(2 * (dk - 1));
            Qx[dk] = fmaf(tv, ch, 99.5f);
            Qy[dk] = fmaf(tv, sh, 99.5f);
        }
        float wv[4];
#pragma unroll
        for (int dj = 0; dj < 4; ++dj) {
            float Px = rv4[dj] * (-sh);
            float Py = rv4[dj] * ch;
            float w = 0.f;
#pragma unroll
            for (int dk = 0; dk < 3; ++dk) {
                float ix = Px + Qx[dk];
                float iy = Py + Qy[dk];
                bool valid = (ix >= 0.f) & (ix <= 199.f) & (iy >= 0.f) & (iy <= 199.f);
                float wx = fmaxf(0.f, 1.f - fabsf(ix - i1f));
                float wy = fmaxf(0.f, 1.f - fabsf(iy - i2f));
                float wxm = valid ? wx : 0.f;
                w = fmaf(wxm, wy, w);
            }
            wv[dj] = w;
        }

#pragma unroll
        for (int dj = 0; dj < 4; ++dj) {
            float w = wv[dj];
            acc[0]  = fmaf(w, Z[dj][0].x, acc[0]);  acc[1]  = fmaf(w, Z[dj][0].y, acc[1]);
            acc[2]  = fmaf(w, Z[dj][0].z, acc[2]);  acc[3]  = fmaf(w, Z[dj][0].w, acc[3]);
            acc[4]  = fmaf(w, Z[dj][1].x, acc[4]);  acc[5]  = fmaf(w, Z[dj][1].y, acc[5]);
            acc[6]  = fmaf(w, Z[dj][1].z, acc[6]);  acc[7]  = fmaf(w, Z[dj][1].w, acc[7]);
            acc[8]  = fmaf(w, Z[dj][2].x, acc[8]);  acc[9]  = fmaf(w, Z[dj][2].y, acc[9]);
            acc[10] = fmaf(w, Z[dj][2].z, acc[10]); acc[11] = fmaf(w, Z[dj][2].w, acc[11]);
            acc[12] = fmaf(w, Z[dj][3].x, acc[12]); acc[13] = fmaf(w, Z[dj][3].y, acc[13]);
            acc[14] = fmaf(w, Z[dj][3].z, acc[14]); acc[15] = fmaf(w, Z[dj][3].w, acc[15]);
        }
    }
#pragma unroll
    for (int i0 = 0; i0 < N0; ++i0)
        atomicAdd(&bp[i0 * NPIX + pix], acc[i0] * 2.0f);  // * STEP
}

extern "C" void kernel_launch(void* const* d_in, const int* in_sizes, int n_in,
                              void* d_out, int out_size, void* d_ws, size_t ws_size,
                              hipStream_t stream) {
    const float* x      = (const float*)d_in[0];
    const float* data   = (const float*)d_in[1];
    const float* contam = (const float*)d_in[2];
    const float* mult   = (const float*)d_in[3];
    const float* sens   = (const float*)d_in[4];
    float* out = (float*)d_out;

    float* W    = (float*)d_ws;
    float* s    = W;                        // 640000 (smoothed; later reused as bp)
    float* tmp  = W + NVOX;                 // 640000
    float* bp2  = W + 2 * NVOX;             // 640000
    float* zt   = W + 3 * NVOX;             // 677920
    float* P    = W + 3 * NVOX + NSINO;     // 4*QS2 = 698880
    float* PT   = P + 4 * QS2;              // 698880
    float* cosb = PT + 4 * QS2;
    float* sinb = cosb + NUM_PHI;
    float* rvb  = sinb + NUM_PHI;
    float* gwb  = rvb + NUM_RAD;

    hipLaunchKernelGGL(init_consts, dim3(1), dim3(256), 0, stream, cosb, sinb, rvb, gwb);

    // gauss3 forward: x -> s (axis0), s -> tmp (axis1), tmp -> {P, PT} (axis2 quad dual-store)
    int nb = (NVOX + 255) / 256;
    hipLaunchKernelGGL(smooth_fwd, dim3(nb), dim3(256), 0, stream, x,   s,   gwb, N0, NPIX);
    hipLaunchKernelGGL(smooth_fwd, dim3(nb), dim3(256), 0, stream, s,   tmp, gwb, N1, N2);
    hipLaunchKernelGGL(smooth_fwd2_quad, dim3(nb), dim3(256), 0, stream, tmp, P, PT, gwb);

    // forward project + ratio (writes zt): 1D grid, quad = b&3 (XCD-pinned)
    hipLaunchKernelGGL(project_ratio, dim3(NUM_PHI * (N0 / 4)), dim3(256, 2), 0, stream,
                       P, PT, data, contam, mult, cosb, sinb, rvb, zt);

    // backproject (gather) into bp (reuse s)
    float* bp = s;
    hipMemsetAsync(bp, 0, NVOX * sizeof(float), stream);
    int nbp = (NPIX + 255) / 256;
    hipLaunchKernelGGL(backproject, dim3(nbp, BP_NCH), dim3(256), 0, stream,
                       zt, cosb, sinb, rvb, bp);

    // gauss3 adjoint: bp -> tmp (axis2^T), tmp -> bp2 (axis1^T), bp2 -> out (axis0^T fused final)
    hipLaunchKernelGGL(smooth_adj, dim3(nb), dim3(256), 0, stream, bp,  tmp, gwb, N2, 1);
    hipLaunchKernelGGL(smooth_adj, dim3(nb), dim3(256), 0, stream, tmp, bp2, gwb, N1, N2);
    hipLaunchKernelGGL(smooth_adj0_final, dim3(nb), dim3(256), 0, stream, bp2, x, sens, gwb, out);
}